// Round 1
// baseline (460.318 us; speedup 1.0000x reference)
//
#include <hip/hip_runtime.h>

#define BS   64
#define CIN  128
#define OCH  128
#define HW   56
#define KEXP 8
#define KTOT 1152          // 9 * 128
#define CPAD 136           // patch cell stride (bf16 elems): 16B-aligned, 2-way-conflict-free

typedef __bf16 bf16x8 __attribute__((ext_vector_type(8)));
typedef float  f32x4  __attribute__((ext_vector_type(4)));

__device__ __forceinline__ unsigned short f2bf(float f) {
    union { float f; unsigned u; } v; v.f = f;
    unsigned r = v.u + 0x7fffu + ((v.u >> 16) & 1u);   // round-to-nearest-even
    return (unsigned short)(r >> 16);
}

// w_mix[b][oc][rs][c] = sum_e rw[b][e] * W[e][oc][c][r][s], stored bf16.
// out idx = ((b*128 + oc)*9 + rs)*128 + c  (c innermost -> conv A-frags contiguous)
__global__ __launch_bounds__(256) void prep_wmix(
        const float* __restrict__ rw, const float* __restrict__ wgt,
        unsigned short* __restrict__ wmix) {
    int base = blockIdx.x * 256;                  // 147456 per b, 576 blocks per b (no straddle)
    int b    = base / (OCH * 9 * CIN);            // block-uniform
    int idx  = base + threadIdx.x;
    int rem  = idx - b * (OCH * 9 * CIN);
    int oc   = rem / (9 * CIN);
    int rem2 = rem - oc * (9 * CIN);
    int rs   = rem2 >> 7;
    int c    = rem2 & 127;
    // W flat: ((e*128 + oc)*128 + c)*9 + rs
    const float* w0 = wgt + ((size_t)oc * CIN + c) * 9 + rs;
    float acc = 0.f;
    #pragma unroll
    for (int e = 0; e < KEXP; ++e)
        acc += rw[b * KEXP + e] * w0[(size_t)e * OCH * CIN * 9];
    wmix[idx] = f2bf(acc);
}

__global__ __launch_bounds__(256) void prep_bmix(
        const float* __restrict__ rw, const float* __restrict__ bias,
        float* __restrict__ bmix) {
    int i  = blockIdx.x * 256 + threadIdx.x;      // 8192 total
    int b  = i >> 7, oc = i & 127;
    float a = 0.f;
    #pragma unroll
    for (int e = 0; e < KEXP; ++e) a += rw[b * KEXP + e] * bias[e * OCH + oc];
    bmix[i] = a;
}

// One block = (sample b, 8x8 output tile). 64 samples * 49 tiles = 3136 blocks.
// Block tile: M=128 oc x N=64 px. 4 waves, wave w covers oc [32w, 32w+32).
// B (input patch) lives in LDS; A (w_mix) streams from global (L2-hot); K-loop barrier-free.
__global__ __launch_bounds__(256) void condconv_mfma(
        const float* __restrict__ x, const unsigned short* __restrict__ wmix,
        const float* __restrict__ bmix, float* __restrict__ out) {
    __shared__ unsigned short patch[100 * CPAD];   // 10x10 cells x 128c (pad->136), 27.2 KB

    int blk = blockIdx.x;
    int b   = blk / 49;
    int t   = blk - b * 49;
    int oh0 = (t / 7) * 8;
    int ow0 = (t - (t / 7) * 7) * 8;

    int tid = threadIdx.x;

    // ---- stage 10x10x128 bf16 patch: item i -> cell p, channel pair cb ----
    // writes: consecutive lanes -> consecutive c -> conflict-free b32 writes
    const float* xb = x + (size_t)b * CIN * HW * HW;
    for (int i = tid; i < 6400; i += 256) {
        int p  = i >> 6;                // 0..99
        int cb = (i & 63) * 2;          // channel pair
        int y  = p / 10, xx = p - y * 10;
        int ih = oh0 + y - 1, iw = ow0 + xx - 1;
        float v0 = 0.f, v1 = 0.f;
        if ((unsigned)ih < (unsigned)HW && (unsigned)iw < (unsigned)HW) {
            const float* r0 = xb + ((size_t)cb * HW + ih) * HW + iw;
            v0 = r0[0];
            v1 = r0[(size_t)HW * HW];
        }
        unsigned pk = (unsigned)f2bf(v0) | ((unsigned)f2bf(v1) << 16);
        *(unsigned*)&patch[p * CPAD + cb] = pk;
    }
    __syncthreads();

    int wave = tid >> 6;
    int lane = tid & 63;
    int ln   = lane & 15;
    int quad = lane >> 4;

    // A-fragment global pointers: A[m = oc][k], lane ln -> oc offset, quad -> k-group
    const unsigned short* wmb = wmix + (size_t)b * OCH * KTOT;
    const unsigned short* a0p = wmb + (size_t)(wave * 32 + ln) * KTOT + quad * 8;
    const unsigned short* a1p = a0p + (size_t)16 * KTOT;

    // B-fragment LDS bases: n = nt*16 + ln -> pixel (y = n>>3, x = n&7)
    int bbase[4];
    #pragma unroll
    for (int nt = 0; nt < 4; ++nt) {
        int n = nt * 16 + ln;
        bbase[nt] = ((n >> 3) * 10 + (n & 7)) * CPAD + quad * 8;
    }

    f32x4 acc[2][4] = {};

    #pragma unroll
    for (int rs = 0; rs < 9; ++rs) {
        const int r = rs / 3;
        const int s = rs - r * 3;
        const int pshift = (r * 10 + s) * CPAD;
        #pragma unroll
        for (int cc = 0; cc < 4; ++cc) {
            const int ko = rs * 128 + cc * 32;
            bf16x8 a0 = *(const bf16x8*)(a0p + ko);
            bf16x8 a1 = *(const bf16x8*)(a1p + ko);
            #pragma unroll
            for (int nt = 0; nt < 4; ++nt) {
                bf16x8 bb = *(const bf16x8*)&patch[bbase[nt] + pshift + cc * 32];
                acc[0][nt] = __builtin_amdgcn_mfma_f32_16x16x32_bf16(a0, bb, acc[0][nt], 0, 0, 0);
                acc[1][nt] = __builtin_amdgcn_mfma_f32_16x16x32_bf16(a1, bb, acc[1][nt], 0, 0, 0);
            }
        }
    }

    // epilogue: C/D layout col = lane&15 (pixel), row = quad*4 + reg (oc)
    const float* bmb = bmix + b * OCH;
    float* ob = out + (size_t)b * OCH * HW * HW;
    #pragma unroll
    for (int mt = 0; mt < 2; ++mt) {
        #pragma unroll
        for (int rg = 0; rg < 4; ++rg) {
            int oc = wave * 32 + mt * 16 + quad * 4 + rg;
            float bv = bmb[oc];
            #pragma unroll
            for (int nt = 0; nt < 4; ++nt) {
                int n  = nt * 16 + ln;
                int oh = oh0 + (n >> 3), ow = ow0 + (n & 7);
                ob[(size_t)oc * (HW * HW) + oh * HW + ow] = acc[mt][nt][rg] + bv;
            }
        }
    }
}

extern "C" void kernel_launch(void* const* d_in, const int* in_sizes, int n_in,
                              void* d_out, int out_size, void* d_ws, size_t ws_size,
                              hipStream_t stream) {
    (void)in_sizes; (void)n_in; (void)out_size; (void)ws_size;
    const float* x    = (const float*)d_in[0];
    const float* rw   = (const float*)d_in[1];
    const float* wgt  = (const float*)d_in[2];
    const float* bias = (const float*)d_in[3];
    float* outp = (float*)d_out;

    unsigned short* wmix = (unsigned short*)d_ws;                       // 18,874,368 B
    float* bmix = (float*)((char*)d_ws + (size_t)BS * OCH * KTOT * 2);  // + 32 KB

    hipLaunchKernelGGL(prep_wmix, dim3((BS * OCH * 9 * CIN) / 256), dim3(256), 0, stream,
                       rw, wgt, wmix);
    hipLaunchKernelGGL(prep_bmix, dim3(32), dim3(256), 0, stream, rw, bias, bmix);
    hipLaunchKernelGGL(condconv_mfma, dim3(BS * 49), dim3(256), 0, stream,
                       x, wmix, bmix, outp);
}

// Round 2
// 336.719 us; speedup vs baseline: 1.3671x; 1.3671x over previous
//
#include <hip/hip_runtime.h>

#define BS   64
#define CIN  128
#define OCH  128
#define HW   56
#define KEXP 8
#define KTOT 1152          // 9 * 128
#define CPAD 136           // patch cell stride (bf16 elems): 272 B = odd # of 16B granules
#define NROW 2             // output rows per block
#define NCOL 56
#define NPX  112           // N per block tile
#define PROWS 4            // patch rows (2 out + 2 halo)
#define PCOLS 58           // 56 + 2 halo
#define PCELLS 232         // 4*58

typedef __bf16 bf16x8 __attribute__((ext_vector_type(8)));
typedef float  f32x4  __attribute__((ext_vector_type(4)));

__device__ __forceinline__ unsigned short f2bf(float f) {
    union { float f; unsigned u; } v; v.f = f;
    unsigned r = v.u + 0x7fffu + ((v.u >> 16) & 1u);   // round-to-nearest-even
    return (unsigned short)(r >> 16);
}

// Block = (oc, b-group of 16). Reads W[e][oc][*] ONCE (coalesced, native flat
// order), mixes 16 samples from LDS-cached rw, writes wmix coalesced.
// wmix[b][oc][k] with k = rs*128 + c  (c innermost within 32-k chunks).
__global__ __launch_bounds__(256) void prep_wmix(
        const float* __restrict__ rw, const float* __restrict__ wgt,
        unsigned short* __restrict__ wmix) {
    __shared__ float wlds[KEXP * KTOT];     // 36.9 KB
    __shared__ float rwl[16 * KEXP];
    int oc  = blockIdx.x;
    int bg  = blockIdx.y;                   // 4 groups of 16 samples
    int tid = threadIdx.x;

    if (tid < 16 * KEXP) rwl[tid] = rw[bg * 16 * KEXP + tid];
    const float* wsrc = wgt + (size_t)oc * KTOT;   // W flat: e*147456 + oc*1152 + (c*9+rs)
    #pragma unroll
    for (int e = 0; e < KEXP; ++e) {
        const float* we = wsrc + (size_t)e * OCH * KTOT;
        for (int j = tid; j < KTOT; j += 256) wlds[e * KTOT + j] = we[j];
    }
    __syncthreads();

    for (int t = tid; t < KTOT; t += 256) {  // t = rs*128 + c (output order)
        int c = t & 127, rs = t >> 7;
        float w8[KEXP];
        #pragma unroll
        for (int e = 0; e < KEXP; ++e) w8[e] = wlds[e * KTOT + c * 9 + rs];
        #pragma unroll
        for (int b = 0; b < 16; ++b) {
            float a = 0.f;
            #pragma unroll
            for (int e = 0; e < KEXP; ++e) a += rwl[b * KEXP + e] * w8[e];
            wmix[((size_t)(bg * 16 + b) * OCH + oc) * KTOT + t] = f2bf(a);
        }
    }
}

__global__ __launch_bounds__(256) void prep_bmix(
        const float* __restrict__ rw, const float* __restrict__ bias,
        float* __restrict__ bmix) {
    int i = blockIdx.x * 256 + threadIdx.x;      // 8192 total
    int b = i >> 7, oc = i & 127;
    float a = 0.f;
    #pragma unroll
    for (int e = 0; e < KEXP; ++e) a += rw[b * KEXP + e] * bias[e * OCH + oc];
    bmix[i] = a;
}

// Block = (sample b, 2-row tile). b = blk & 63 so a sample's 28 tiles are 64
// blocks apart -> same XCD -> wmix stays L2-resident. M=128 x N=112 per block,
// 4 waves (32 oc each). B (x patch) in LDS, read once, reused over all 9 taps.
// A (wmix) streams from L2 with a depth-1 register double-buffer.
__global__ __launch_bounds__(256, 2) void condconv_mfma(
        const float* __restrict__ x, const unsigned short* __restrict__ wmix,
        const float* __restrict__ bmix, float* __restrict__ out) {
    __shared__ unsigned short patch[PCELLS * CPAD];   // 63.1 KB -> 2 blocks/CU

    int blk  = blockIdx.x;
    int b    = blk & 63;
    int tile = blk >> 6;               // 0..27
    int oh0  = tile * NROW;
    int tid  = threadIdx.x;
    int wave = tid >> 6, lane = tid & 63, ln = lane & 15, quad = lane >> 4;

    // A pointers + prefetch step 0 (before barrier: overlaps staging)
    const unsigned short* wmb = wmix + (size_t)b * OCH * KTOT;
    const unsigned short* a0p = wmb + (size_t)(wave * 32 + ln) * KTOT + quad * 8;
    const unsigned short* a1p = a0p + (size_t)16 * KTOT;
    bf16x8 ac0 = *(const bf16x8*)a0p;
    bf16x8 ac1 = *(const bf16x8*)a1p;

    // ---- stage patch: lanes <-> consecutive columns (coalesced global reads),
    //      4 channels per thread, one 8-B LDS write (transpose in the write) ----
    const float* xb = x + (size_t)b * CIN * HW * HW;
    #pragma unroll 4
    for (int it = 0; it < 32; ++it) {
        int i   = it * 256 + tid;
        int c   = (i >> 8) * 4;        // channel quad
        int y   = (i >> 6) & 3;        // patch row
        int col = i & 63;              // patch col (+halo)
        if (col < PCOLS) {
            int ih = oh0 + y - 1;
            int iw = col - 1;
            float v0 = 0.f, v1 = 0.f, v2 = 0.f, v3 = 0.f;
            if ((unsigned)ih < 56u && (unsigned)iw < 56u) {
                const float* r0 = xb + ((size_t)c * HW + ih) * HW + iw;
                v0 = r0[0];
                v1 = r0[HW * HW];
                v2 = r0[2 * HW * HW];
                v3 = r0[3 * HW * HW];
            }
            unsigned p0 = (unsigned)f2bf(v0) | ((unsigned)f2bf(v1) << 16);
            unsigned p1 = (unsigned)f2bf(v2) | ((unsigned)f2bf(v3) << 16);
            int cell = y * PCOLS + col;
            *(uint2*)&patch[cell * CPAD + c] = make_uint2(p0, p1);
        }
    }
    __syncthreads();

    // B-fragment bases + output offsets: n = nt*16 + ln -> (row, ow)
    int bb[7], offn[7];
    #pragma unroll
    for (int nt = 0; nt < 7; ++nt) {
        int n   = nt * 16 + ln;
        int row = (n >= NCOL) ? 1 : 0;
        int ow  = n - row * NCOL;
        bb[nt]   = (row * PCOLS + ow) * CPAD + quad * 8;
        offn[nt] = (oh0 + row) * HW + ow;
    }

    f32x4 acc[2][7] = {};

    // K-loop: s = rs*4 + cc, k-offset = 32*s. Prefetch A for s+1, then 14 MFMA.
    #pragma unroll
    for (int s = 0; s < 36; ++s) {
        bf16x8 an0 = ac0, an1 = ac1;
        if (s < 35) {
            int ko = (s + 1) * 32;
            an0 = *(const bf16x8*)(a0p + ko);
            an1 = *(const bf16x8*)(a1p + ko);
        }
        const int rs = s >> 2, cc = s & 3;
        const int r = rs / 3, sc = rs - r * 3;
        const int pshift = (r * PCOLS + sc) * CPAD + cc * 32;
        #pragma unroll
        for (int nt = 0; nt < 7; ++nt) {
            bf16x8 bbf = *(const bf16x8*)&patch[bb[nt] + pshift];
            acc[0][nt] = __builtin_amdgcn_mfma_f32_16x16x32_bf16(ac0, bbf, acc[0][nt], 0, 0, 0);
            acc[1][nt] = __builtin_amdgcn_mfma_f32_16x16x32_bf16(ac1, bbf, acc[1][nt], 0, 0, 0);
        }
        ac0 = an0; ac1 = an1;
    }

    // epilogue: D layout col(lane&15)=pixel, row(quad*4+reg)=oc
    const float* bmb = bmix + b * OCH;
    float* ob = out + (size_t)b * OCH * HW * HW;
    #pragma unroll
    for (int mt = 0; mt < 2; ++mt) {
        #pragma unroll
        for (int rg = 0; rg < 4; ++rg) {
            int oc = wave * 32 + mt * 16 + quad * 4 + rg;
            float bv = bmb[oc];
            #pragma unroll
            for (int nt = 0; nt < 7; ++nt)
                ob[(size_t)oc * (HW * HW) + offn[nt]] = acc[mt][nt][rg] + bv;
        }
    }
}

extern "C" void kernel_launch(void* const* d_in, const int* in_sizes, int n_in,
                              void* d_out, int out_size, void* d_ws, size_t ws_size,
                              hipStream_t stream) {
    (void)in_sizes; (void)n_in; (void)out_size; (void)ws_size;
    const float* x    = (const float*)d_in[0];
    const float* rw   = (const float*)d_in[1];
    const float* wgt  = (const float*)d_in[2];
    const float* bias = (const float*)d_in[3];
    float* outp = (float*)d_out;

    unsigned short* wmix = (unsigned short*)d_ws;                       // 18,874,368 B
    float* bmix = (float*)((char*)d_ws + (size_t)BS * OCH * KTOT * 2);  // + 32 KB

    hipLaunchKernelGGL(prep_wmix, dim3(OCH, 4), dim3(256), 0, stream, rw, wgt, wmix);
    hipLaunchKernelGGL(prep_bmix, dim3(32), dim3(256), 0, stream, rw, bias, bmix);
    hipLaunchKernelGGL(condconv_mfma, dim3(BS * 28), dim3(256), 0, stream,
                       x, wmix, bmix, outp);
}

// Round 3
// 294.698 us; speedup vs baseline: 1.5620x; 1.1426x over previous
//
#include <hip/hip_runtime.h>

#define BS   64
#define CIN  128
#define OCH  128
#define HW   56
#define KEXP 8
#define KTOT 1152          // 9 * 128
#define PCOLS 58           // 56 + 2 halo
#define PROWS 4            // 2 output rows + 2 halo
#define PCELLS 232         // 4*58
#define CPAD  68           // bf16 per cell (64 ch + 4 pad) = 34 words ≡ 2 mod 32 -> conflict-free

typedef __bf16 bf16x8 __attribute__((ext_vector_type(8)));
typedef __bf16 bf16x4 __attribute__((ext_vector_type(4)));
typedef float  f32x4  __attribute__((ext_vector_type(4)));

__device__ __forceinline__ unsigned f2bf(float f) {
    union { float f; unsigned u; } v; v.f = f;
    unsigned r = v.u + 0x7fffu + ((v.u >> 16) & 1u);   // RNE
    return r >> 16;
}

// k-offset (bf16 elems) into wmix row for pipeline step s (0..35):
// half h = s/18, tap rs = (s%18)/2, chunk cc = s%2; k = rs*128 + h*64 + cc*32
__device__ constexpr int KO(int s) {
    int h = s / 18, t = s - h * 18;
    return (t >> 1) * 128 + h * 64 + (t & 1) * 32;
}

// Block = (oc, b-group of 16). Reads W[e][oc][*] once (coalesced), mixes 16
// samples, writes wmix[b][oc][k] bf16, k = rs*128 + c.
__global__ __launch_bounds__(256) void prep_wmix(
        const float* __restrict__ rw, const float* __restrict__ wgt,
        unsigned short* __restrict__ wmix) {
    __shared__ float wlds[KEXP * KTOT];     // 36.9 KB
    __shared__ float rwl[16 * KEXP];
    int oc  = blockIdx.x;
    int bg  = blockIdx.y;
    int tid = threadIdx.x;

    if (tid < 16 * KEXP) rwl[tid] = rw[bg * 16 * KEXP + tid];
    const float* wsrc = wgt + (size_t)oc * KTOT;
    #pragma unroll
    for (int e = 0; e < KEXP; ++e) {
        const float* we = wsrc + (size_t)e * OCH * KTOT;
        for (int j = tid; j < KTOT; j += 256) wlds[e * KTOT + j] = we[j];
    }
    __syncthreads();

    for (int t = tid; t < KTOT; t += 256) {
        int c = t & 127, rs = t >> 7;
        float w8[KEXP];
        #pragma unroll
        for (int e = 0; e < KEXP; ++e) w8[e] = wlds[e * KTOT + c * 9 + rs];
        #pragma unroll
        for (int b = 0; b < 16; ++b) {
            float a = 0.f;
            #pragma unroll
            for (int e = 0; e < KEXP; ++e) a += rwl[b * KEXP + e] * w8[e];
            wmix[((size_t)(bg * 16 + b) * OCH + oc) * KTOT + t] = (unsigned short)f2bf(a);
        }
    }
}

__global__ __launch_bounds__(256) void prep_bmix(
        const float* __restrict__ rw, const float* __restrict__ bias,
        float* __restrict__ bmix) {
    int i = blockIdx.x * 256 + threadIdx.x;
    int b = i >> 7, oc = i & 127;
    float a = 0.f;
    #pragma unroll
    for (int e = 0; e < KEXP; ++e) a += rw[b * KEXP + e] * bias[e * OCH + oc];
    bmix[i] = a;
}

// Block = (sample b, 2-row tile), b = blk&63 (XCD-locality for wmix).
// M=128 x N=112, 4 waves (32 oc each). Patch staged in TWO 64-channel halves
// (31.6 KB LDS -> 4 blocks/CU -> 16 waves/CU). A streams from L2 with a
// depth-2 register pipeline that runs across the half boundary.
__global__ __launch_bounds__(256, 4) void condconv_mfma(
        const float* __restrict__ x, const unsigned short* __restrict__ wmix,
        const float* __restrict__ bmix, float* __restrict__ out) {
    __shared__ unsigned short patch[PCELLS * CPAD];   // 31,552 B

    int blk  = blockIdx.x;
    int b    = blk & 63;
    int tile = blk >> 6;               // 0..27
    int oh0  = tile * 2;
    int tid  = threadIdx.x;
    int wave = tid >> 6, lane = tid & 63, ln = lane & 15, quad = lane >> 4;

    const unsigned short* wmb = wmix + (size_t)b * OCH * KTOT;
    const unsigned short* a0p = wmb + (size_t)(wave * 32 + ln) * KTOT + quad * 8;
    const unsigned short* a1p = a0p + (size_t)16 * KTOT;

    // depth-2 A pipeline: preload steps 0,1 (in flight during staging)
    bf16x8 pa0[2], pa1[2];
    pa0[0] = *(const bf16x8*)(a0p + KO(0));
    pa1[0] = *(const bf16x8*)(a1p + KO(0));
    pa0[1] = *(const bf16x8*)(a0p + KO(1));
    pa1[1] = *(const bf16x8*)(a1p + KO(1));

    const float* xb = x + (size_t)b * CIN * HW * HW;
    auto stage = [&](int h) {
        const float* xh = xb + (size_t)h * 64 * HW * HW;
        #pragma unroll 4
        for (int it = 0; it < 16; ++it) {
            int i   = it * 256 + tid;
            int col = i & 63;              // patch col
            int y   = (i >> 6) & 3;        // patch row
            int cq  = i >> 8;              // channel quad within half (0..15)
            if (col < PCOLS) {
                int ih = oh0 + y - 1, iw = col - 1;
                float v0 = 0.f, v1 = 0.f, v2 = 0.f, v3 = 0.f;
                if ((unsigned)ih < 56u && (unsigned)iw < 56u) {
                    const float* r0 = xh + ((size_t)(cq * 4) * HW + ih) * HW + iw;
                    v0 = r0[0];
                    v1 = r0[HW * HW];
                    v2 = r0[2 * HW * HW];
                    v3 = r0[3 * HW * HW];
                }
                unsigned p0 = f2bf(v0) | (f2bf(v1) << 16);
                unsigned p1 = f2bf(v2) | (f2bf(v3) << 16);
                int cell = y * PCOLS + col;
                *(uint2*)&patch[cell * CPAD + cq * 4] = make_uint2(p0, p1);
            }
        }
    };

    // B bases + output offsets: n = nt*16 + ln
    int cbq[7], offn[7];
    #pragma unroll
    for (int nt = 0; nt < 7; ++nt) {
        int n   = nt * 16 + ln;
        int row = (n >= 56) ? 1 : 0;
        int ow  = n - row * 56;
        cbq[nt]  = (row * PCOLS + ow) * CPAD + quad * 8;
        offn[nt] = (oh0 + row) * HW + ow;
    }

    f32x4 acc[2][7] = {};

    stage(0);
    __syncthreads();
    #pragma unroll
    for (int t = 0; t < 18; ++t) {
        bf16x8 ca0 = pa0[t & 1], ca1 = pa1[t & 1];
        pa0[t & 1] = *(const bf16x8*)(a0p + KO(t + 2));   // t+2 <= 19: valid
        pa1[t & 1] = *(const bf16x8*)(a1p + KO(t + 2));
        const int rs = t >> 1, cc = t & 1;
        const int r = rs / 3, sc = rs - r * 3;
        const int pshift = (r * PCOLS + sc) * CPAD + cc * 32;
        #pragma unroll
        for (int nt = 0; nt < 7; ++nt) {
            int boff = cbq[nt] + pshift;
            bf16x4 lo = *(const bf16x4*)&patch[boff];
            bf16x4 hi = *(const bf16x4*)&patch[boff + 4];
            bf16x8 bb = __builtin_shufflevector(lo, hi, 0, 1, 2, 3, 4, 5, 6, 7);
            acc[0][nt] = __builtin_amdgcn_mfma_f32_16x16x32_bf16(ca0, bb, acc[0][nt], 0, 0, 0);
            acc[1][nt] = __builtin_amdgcn_mfma_f32_16x16x32_bf16(ca1, bb, acc[1][nt], 0, 0, 0);
        }
    }
    __syncthreads();     // all waves done reading half 0
    stage(1);
    __syncthreads();
    #pragma unroll
    for (int t = 18; t < 36; ++t) {
        bf16x8 ca0 = pa0[t & 1], ca1 = pa1[t & 1];
        if (t < 34) {
            pa0[t & 1] = *(const bf16x8*)(a0p + KO(t + 2));
            pa1[t & 1] = *(const bf16x8*)(a1p + KO(t + 2));
        }
        const int tt = t - 18;
        const int rs = tt >> 1, cc = tt & 1;
        const int r = rs / 3, sc = rs - r * 3;
        const int pshift = (r * PCOLS + sc) * CPAD + cc * 32;
        #pragma unroll
        for (int nt = 0; nt < 7; ++nt) {
            int boff = cbq[nt] + pshift;
            bf16x4 lo = *(const bf16x4*)&patch[boff];
            bf16x4 hi = *(const bf16x4*)&patch[boff + 4];
            bf16x8 bb = __builtin_shufflevector(lo, hi, 0, 1, 2, 3, 4, 5, 6, 7);
            acc[0][nt] = __builtin_amdgcn_mfma_f32_16x16x32_bf16(ca0, bb, acc[0][nt], 0, 0, 0);
            acc[1][nt] = __builtin_amdgcn_mfma_f32_16x16x32_bf16(ca1, bb, acc[1][nt], 0, 0, 0);
        }
    }

    // epilogue: D layout col(lane&15)=pixel, row(quad*4+reg)=oc
    const float* bmb = bmix + b * OCH;
    float* ob = out + (size_t)b * OCH * HW * HW;
    #pragma unroll
    for (int mt = 0; mt < 2; ++mt) {
        #pragma unroll
        for (int rg = 0; rg < 4; ++rg) {
            int oc = wave * 32 + mt * 16 + quad * 4 + rg;
            float bv = bmb[oc];
            #pragma unroll
            for (int nt = 0; nt < 7; ++nt)
                ob[(size_t)oc * (HW * HW) + offn[nt]] = acc[mt][nt][rg] + bv;
        }
    }
}

extern "C" void kernel_launch(void* const* d_in, const int* in_sizes, int n_in,
                              void* d_out, int out_size, void* d_ws, size_t ws_size,
                              hipStream_t stream) {
    (void)in_sizes; (void)n_in; (void)out_size; (void)ws_size;
    const float* x    = (const float*)d_in[0];
    const float* rw   = (const float*)d_in[1];
    const float* wgt  = (const float*)d_in[2];
    const float* bias = (const float*)d_in[3];
    float* outp = (float*)d_out;

    unsigned short* wmix = (unsigned short*)d_ws;                       // 18,874,368 B
    float* bmix = (float*)((char*)d_ws + (size_t)BS * OCH * KTOT * 2);  // + 32 KB

    hipLaunchKernelGGL(prep_wmix, dim3(OCH, 4), dim3(256), 0, stream, rw, wgt, wmix);
    hipLaunchKernelGGL(prep_bmix, dim3(32), dim3(256), 0, stream, rw, bias, bmix);
    hipLaunchKernelGGL(condconv_mfma, dim3(BS * 28), dim3(256), 0, stream,
                       x, wmix, bmix, outp);
}